// Round 1
// baseline (684.350 us; speedup 1.0000x reference)
//
#include <hip/hip_runtime.h>
#include <hip/hip_bf16.h>
#include <math.h>

#define NPTS   4096
#define NB     4
#define NC     61
#define NIN    64
#define NOUT   128
#define NK     16
#define NROWS  16384           // NB*NPTS
#define BN_EPS 1e-5f
#define INV_ROWS (1.0f/16384.0f)

// ---------------------------------------------------------------------------
// Kernel 1: exact KNN (top-16 smallest d2, stable tie-break by index).
// 512 blocks x 256 threads; 32 queries/block, 8 lanes/query.
// Lane L scans candidates j with j % 8 == L (keeps wave loads on ~2 lines).
// ---------------------------------------------------------------------------
__global__ __launch_bounds__(256) void knn_kernel(const float* __restrict__ pos,
                                                  int* __restrict__ idx_out) {
    __shared__ float md[32 * 128];
    __shared__ int   mi[32 * 128];
    const int t  = threadIdx.x;
    const int b  = blockIdx.x >> 7;            // 128 blocks per batch
    const int q0 = (blockIdx.x & 127) * 32;
    const float* __restrict__ pb = pos + b * (NPTS * 3);

    const int qloc = t >> 3;
    const int l8   = t & 7;
    const int qi   = q0 + qloc;

    const float qx = pb[qi * 3 + 0];
    const float qy = pb[qi * 3 + 1];
    const float qz = pb[qi * 3 + 2];

    float bd[16];
    int   bi[16];
#pragma unroll
    for (int i = 0; i < 16; ++i) { bd[i] = 1e30f; bi[i] = 0x7fffffff; }

#pragma unroll 2
    for (int jj = 0; jj < NPTS / 8; ++jj) {
        const int j = (jj << 3) | l8;
        const float cx = pb[j * 3 + 0];
        const float cy = pb[j * 3 + 1];
        const float cz = pb[j * 3 + 2];
        const float dx = qx - cx, dy = qy - cy, dz = qz - cz;
        // match numpy fp32 exactly: squares + sequential adds, no contraction
        const float d2 = __fadd_rn(__fadd_rn(__fmul_rn(dx, dx), __fmul_rn(dy, dy)),
                                   __fmul_rn(dz, dz));
        if (d2 < bd[15]) {
            bd[15] = d2; bi[15] = j;
#pragma unroll
            for (int i = 15; i > 0; --i) {
                const float d_hi = bd[i - 1], d_lo = bd[i];
                const int   i_hi = bi[i - 1], i_lo = bi[i];
                const bool  sw = d_lo < d_hi;
                bd[i - 1] = sw ? d_lo : d_hi;
                bd[i]     = sw ? d_hi : d_lo;
                bi[i - 1] = sw ? i_lo : i_hi;
                bi[i]     = sw ? i_hi : i_lo;
            }
        }
    }

    const int mbase = qloc * 128 + l8 * 16;
#pragma unroll
    for (int i = 0; i < 16; ++i) { md[mbase + i] = bd[i]; mi[mbase + i] = bi[i]; }
    __syncthreads();

    if (l8 == 0) {
        int hp[8] = {0, 0, 0, 0, 0, 0, 0, 0};
        const int ob = ((b << 12) | qi) * NK;
        for (int o = 0; o < NK; ++o) {
            float bestd = 1e38f; int bestj = 0x7fffffff; int bestL = 0;
#pragma unroll
            for (int L = 0; L < 8; ++L) {
                const int h = hp[L];
                const bool valid = h < 16;
                const int a = qloc * 128 + L * 16 + (valid ? h : 15);
                const float d = valid ? md[a] : 1e38f;
                const int   jv = valid ? mi[a] : 0x7fffffff;
                const bool better = (d < bestd) || ((d == bestd) && (jv < bestj));
                bestd = better ? d : bestd;
                bestj = better ? jv : bestj;
                bestL = better ? L : bestL;
            }
            idx_out[ob + o] = bestj;
#pragma unroll
            for (int L = 0; L < 8; ++L) hp[L] += (L == bestL) ? 1 : 0;
        }
    }
}

// ---------------------------------------------------------------------------
// Kernel 2: relation MLP (10->32->64->64) + weighted max-pool over K.
// One thread per (query, k). 16 lanes of a query = one shfl group.
// ---------------------------------------------------------------------------
__global__ __launch_bounds__(256) void mlp_kernel(
    const float* __restrict__ pos, const float* __restrict__ x,
    const int* __restrict__ idx,
    const float* __restrict__ rw1, const float* __restrict__ rb1,
    const float* __restrict__ rw2, const float* __restrict__ rb2,
    const float* __restrict__ rw3, const float* __restrict__ rb3,
    float* __restrict__ pooled) {
    __shared__ float w1s[320], w2s[2048], w3t[4096], b1s[32], b2s[64], b3s[64];
    const int t = threadIdx.x;
    for (int i = t; i < 320; i += 256)  w1s[i] = rw1[i];
    for (int i = t; i < 2048; i += 256) w2s[i] = rw2[i];
    for (int i = t; i < 4096; i += 256) {                 // transpose rw3 -> w3t[o][i]
        const int ii = i >> 6, oo = i & 63;
        w3t[oo * 64 + ii] = rw3[i];
    }
    if (t < 32)                 b1s[t] = rb1[t];
    else if (t >= 32 && t < 96) b2s[t - 32] = rb2[t - 32];
    else if (t >= 96 && t < 160) b3s[t - 96] = rb3[t - 96];
    __syncthreads();

    const int g = blockIdx.x * 256 + t;
    const int k = g & 15;
    const int q = g >> 4;                    // 0..16383
    const int b = q >> 12, n = q & 4095;
    const int j = idx[(size_t)q * NK + k];
    const float* __restrict__ pb = pos + b * (NPTS * 3);

    const float cx = pb[n * 3 + 0], cy = pb[n * 3 + 1], cz = pb[n * 3 + 2];
    const float gx = pb[j * 3 + 0], gy = pb[j * 3 + 1], gz = pb[j * 3 + 2];
    const float rx = gx - cx, ry = gy - cy, rz = gz - cz;
    const float ss = rx * rx + ry * ry + rz * rz;
    const float dis = (ss > 0.f) ? sqrtf(ss) : 0.f;
    const float rin[10] = {cx, cy, cz, gx, gy, gz, rx, ry, rz, dis};

    float h1[32];
#pragma unroll
    for (int o = 0; o < 32; ++o) h1[o] = b1s[o];
#pragma unroll
    for (int i = 0; i < 10; ++i) {
        const float v = rin[i];
#pragma unroll
        for (int o = 0; o < 32; ++o) h1[o] += v * w1s[i * 32 + o];
    }
#pragma unroll
    for (int o = 0; o < 32; ++o) h1[o] = fmaxf(h1[o], 0.f);

    float h2[64];
#pragma unroll
    for (int o = 0; o < 64; ++o) h2[o] = b2s[o];
#pragma unroll
    for (int i = 0; i < 32; ++i) {
        const float v = h1[i];
#pragma unroll
        for (int o = 0; o < 64; ++o) h2[o] += v * w2s[i * 64 + o];
    }
#pragma unroll
    for (int o = 0; o < 64; ++o) h2[o] = fmaxf(h2[o], 0.f);

    const float* __restrict__ xr = x + (size_t)((b << 12) | j) * NC;
    float* __restrict__ pout = pooled + (size_t)q * 64;

    for (int o = 0; o < 64; ++o) {
        float acc = b3s[o];
#pragma unroll
        for (int i = 0; i < 64; i += 4) {
            const float4 wv = *(const float4*)&w3t[o * 64 + i];
            acc += h2[i] * wv.x + h2[i + 1] * wv.y + h2[i + 2] * wv.z + h2[i + 3] * wv.w;
        }
        float f = (o < NC) ? xr[o] : (o == 61 ? gx : (o == 62 ? gy : gz));
        f *= acc;
#pragma unroll
        for (int m = 1; m < 16; m <<= 1) f = fmaxf(f, __shfl_xor(f, m, 16));
        if (k == 0) pout[o] = fmaxf(f, 0.f);   // relu AFTER max-pool
    }
}

// ---------------------------------------------------------------------------
// Kernel 3: y1 = pooled(16384x64) @ fw1(64x128) + fb1 ; accumulate sum/sumsq.
// ---------------------------------------------------------------------------
__global__ __launch_bounds__(256) void gemm1_kernel(
    const float* __restrict__ A, const float* __restrict__ W,
    const float* __restrict__ bias, float* __restrict__ y,
    float* __restrict__ sum, float* __restrict__ sumsq) {
    __shared__ float As[64 * 64];
    __shared__ float Bs[64 * 128];
    const int t = threadIdx.x;
    const int r0 = blockIdx.x * 64;
    for (int i = t; i < 64 * 128; i += 256) Bs[i] = W[i];
    for (int i = t; i < 64 * 64; i += 256)  As[i] = A[(size_t)r0 * 64 + i];
    __syncthreads();

    const int c = t & 127, rg = t >> 7;
    float acc[32];
    const float bv = bias[c];
#pragma unroll
    for (int r = 0; r < 32; ++r) acc[r] = bv;

    for (int kk = 0; kk < 64; kk += 4) {
        const float b0 = Bs[(kk + 0) * 128 + c];
        const float b1 = Bs[(kk + 1) * 128 + c];
        const float b2 = Bs[(kk + 2) * 128 + c];
        const float b3 = Bs[(kk + 3) * 128 + c];
#pragma unroll
        for (int r = 0; r < 32; ++r) {
            const float4 a = *(const float4*)&As[(rg * 32 + r) * 64 + kk];
            acc[r] += a.x * b0 + a.y * b1 + a.z * b2 + a.w * b3;
        }
    }

    float s = 0.f, s2 = 0.f;
#pragma unroll
    for (int r = 0; r < 32; ++r) {
        const float v = acc[r];
        s += v; s2 += v * v;
        y[(size_t)(r0 + rg * 32 + r) * 128 + c] = v;
    }
    __syncthreads();
    As[t] = s; As[256 + t] = s2;
    __syncthreads();
    if (rg == 0) {
        atomicAdd(&sum[c],   As[c] + As[128 + c]);
        atomicAdd(&sumsq[c], As[256 + c] + As[256 + 128 + c]);
    }
}

// ---------------------------------------------------------------------------
// Kernel 4: h1 = relu(bn1(y1)); y2 = h1 @ fw2(128x128) + fb2 ; sum/sumsq.
// BN1 scale/shift computed from sum1/sumsq1 in-kernel. K split 2x64 (<=64KB LDS).
// ---------------------------------------------------------------------------
__global__ __launch_bounds__(256) void gemm2_kernel(
    const float* __restrict__ y1, const float* __restrict__ W,
    const float* __restrict__ bias,
    const float* __restrict__ sum1, const float* __restrict__ sumsq1,
    const float* __restrict__ g1, const float* __restrict__ b1,
    float* __restrict__ y2, float* __restrict__ sum2, float* __restrict__ sumsq2) {
    __shared__ float As[64 * 128];
    __shared__ float Bs[64 * 128];
    __shared__ float a1s[128], s1s[128];
    const int t = threadIdx.x;
    const int r0 = blockIdx.x * 64;

    if (t < 128) {
        const float m = sum1[t] * INV_ROWS;
        const float v = sumsq1[t] * INV_ROWS - m * m;
        const float a = rsqrtf(v + BN_EPS) * g1[t];
        a1s[t] = a; s1s[t] = b1[t] - m * a;
    }
    for (int i = t; i < 64 * 128; i += 256) Bs[i] = W[i];   // fw2 rows 0..63
    __syncthreads();
    for (int i = t; i < 64 * 128; i += 256) {
        const int cc = i & 127;
        const float v = y1[(size_t)r0 * 128 + i];
        As[i] = fmaxf(v * a1s[cc] + s1s[cc], 0.f);
    }
    __syncthreads();

    const int c = t & 127, rg = t >> 7;
    float acc[32];
    const float bv = bias[c];
#pragma unroll
    for (int r = 0; r < 32; ++r) acc[r] = bv;

    for (int kk = 0; kk < 64; kk += 4) {
        const float b0 = Bs[(kk + 0) * 128 + c];
        const float b1v = Bs[(kk + 1) * 128 + c];
        const float b2 = Bs[(kk + 2) * 128 + c];
        const float b3 = Bs[(kk + 3) * 128 + c];
#pragma unroll
        for (int r = 0; r < 32; ++r) {
            const float4 a = *(const float4*)&As[(rg * 32 + r) * 128 + kk];
            acc[r] += a.x * b0 + a.y * b1v + a.z * b2 + a.w * b3;
        }
    }
    __syncthreads();
    for (int i = t; i < 64 * 128; i += 256) Bs[i] = W[64 * 128 + i];  // rows 64..127
    __syncthreads();
    for (int kk = 0; kk < 64; kk += 4) {
        const float b0 = Bs[(kk + 0) * 128 + c];
        const float b1v = Bs[(kk + 1) * 128 + c];
        const float b2 = Bs[(kk + 2) * 128 + c];
        const float b3 = Bs[(kk + 3) * 128 + c];
#pragma unroll
        for (int r = 0; r < 32; ++r) {
            const float4 a = *(const float4*)&As[(rg * 32 + r) * 128 + 64 + kk];
            acc[r] += a.x * b0 + a.y * b1v + a.z * b2 + a.w * b3;
        }
    }

    float s = 0.f, s2 = 0.f;
#pragma unroll
    for (int r = 0; r < 32; ++r) {
        const float v = acc[r];
        s += v; s2 += v * v;
        y2[(size_t)(r0 + rg * 32 + r) * 128 + c] = v;
    }
    __syncthreads();
    As[t] = s; As[256 + t] = s2;
    __syncthreads();
    if (rg == 0) {
        atomicAdd(&sum2[c],   As[c] + As[128 + c]);
        atomicAdd(&sumsq2[c], As[256 + c] + As[256 + 128 + c]);
    }
}

// ---------------------------------------------------------------------------
// Kernel 5: out = bn2(y2)  (no relu on the final stage)
// ---------------------------------------------------------------------------
__global__ __launch_bounds__(256) void bnout_kernel(
    const float* __restrict__ y2, const float* __restrict__ sum2,
    const float* __restrict__ sumsq2, const float* __restrict__ g2,
    const float* __restrict__ b2, float* __restrict__ out) {
    const int i = blockIdx.x * 256 + threadIdx.x;
    const int c = i & 127;
    const float m = sum2[c] * INV_ROWS;
    const float v = sumsq2[c] * INV_ROWS - m * m;
    const float a = rsqrtf(v + BN_EPS) * g2[c];
    out[i] = y2[i] * a + (b2[c] - m * a);
}

extern "C" void kernel_launch(void* const* d_in, const int* in_sizes, int n_in,
                              void* d_out, int out_size, void* d_ws, size_t ws_size,
                              hipStream_t stream) {
    const float* x   = (const float*)d_in[0];
    const float* pos = (const float*)d_in[1];
    const float* rw1 = (const float*)d_in[2];
    const float* rb1 = (const float*)d_in[3];
    const float* rw2 = (const float*)d_in[4];
    const float* rb2 = (const float*)d_in[5];
    const float* rw3 = (const float*)d_in[6];
    const float* rb3 = (const float*)d_in[7];
    const float* fw1 = (const float*)d_in[8];
    const float* fb1 = (const float*)d_in[9];
    const float* g1  = (const float*)d_in[10];
    const float* b1  = (const float*)d_in[11];
    const float* fw2 = (const float*)d_in[12];
    const float* fb2 = (const float*)d_in[13];
    const float* g2  = (const float*)d_in[14];
    const float* b2  = (const float*)d_in[15];
    float* out = (float*)d_out;

    char* ws = (char*)d_ws;
    int*   idx    = (int*)ws;                          // 16384*16 ints   (1 MB)
    float* pooled = (float*)(ws + (1u << 20));         // 16384*64 f32    (4 MB)
    float* y1     = (float*)(ws + (5u << 20));         // 16384*128 f32   (8 MB)
    float* y2     = (float*)(ws + (13u << 20));        // 16384*128 f32   (8 MB)
    float* stats  = (float*)(ws + (21u << 20));        // 4*128 f32
    float* sum1 = stats, *sumsq1 = stats + 128, *sum2 = stats + 256, *sumsq2 = stats + 384;

    hipMemsetAsync(stats, 0, 512 * sizeof(float), stream);

    knn_kernel<<<512, 256, 0, stream>>>(pos, idx);
    mlp_kernel<<<1024, 256, 0, stream>>>(pos, x, idx, rw1, rb1, rw2, rb2, rw3, rb3, pooled);
    gemm1_kernel<<<256, 256, 0, stream>>>(pooled, fw1, fb1, y1, sum1, sumsq1);
    gemm2_kernel<<<256, 256, 0, stream>>>(y1, fw2, fb2, sum1, sumsq1, g1, b1, y2, sum2, sumsq2);
    bnout_kernel<<<NROWS * 128 / 256, 256, 0, stream>>>(y2, sum2, sumsq2, g2, b2, out);
}

// Round 3
// 416.959 us; speedup vs baseline: 1.6413x; 1.6413x over previous
//
#include <hip/hip_runtime.h>
#include <hip/hip_bf16.h>
#include <math.h>

#define NPTS   4096
#define NB     4
#define NC     61
#define NIN    64
#define NOUT   128
#define NK     16
#define NROWS  16384           // NB*NPTS
#define BN_EPS 1e-5f
#define INV_ROWS (1.0f/16384.0f)

// ---------------------------------------------------------------------------
// Kernel 1: exact KNN (top-16 smallest d2, tie-break by smaller index).
// 512 blocks x 256 threads; 32 queries/block, 8 lanes/query (lane L scans
// j % 8 == L). Selection via packed u64 keys (d2_bits<<32 | idx):
//  - register-resident sorted top-16 per lane
//  - cheap scan: d2 + compare vs threshold; passing candidates appended to a
//    per-lane LDS ring (2-instr body) instead of an O(16) insert
//  - wave-uniform compaction (bitonic sort 16 + bitonic merge 16+16) only
//    when any lane's ring nears full
// Round-2 bug: group loop ran 16 iters (64 candidates/lane) instead of 128
// (512 candidates/lane) -> only 1/8 of points scanned. Fixed: g < 128.
// ---------------------------------------------------------------------------
#define OCAP 16
#define NPAD 257               // column stride (entries) -> conflict-free

__global__ __launch_bounds__(256) void knn_kernel(const float* __restrict__ pos,
                                                  int* __restrict__ idx_out) {
    __shared__ unsigned long long buf[OCAP * NPAD];
    const int t  = threadIdx.x;
    const int b  = blockIdx.x >> 7;            // 128 blocks per batch
    const int q0 = (blockIdx.x & 127) * 32;
    const float* __restrict__ pb = pos + b * (NPTS * 3);

    const int qloc = t >> 3;
    const int l8   = t & 7;
    const int qi   = q0 + qloc;

    const float qx = pb[qi * 3 + 0];
    const float qy = pb[qi * 3 + 1];
    const float qz = pb[qi * 3 + 2];

    unsigned long long bk[16];
#pragma unroll
    for (int i = 0; i < 16; ++i) bk[i] = ~0ull;
    unsigned int thr_bits = 0xFFFFFFFFu;
    int owptr = 0;

    auto compact = [&]() {
        unsigned long long od[16];
#pragma unroll
        for (int s = 0; s < OCAP; ++s) {
            const unsigned long long v = buf[s * NPAD + t];
            od[s] = (s < owptr) ? v : ~0ull;
        }
        owptr = 0;
        // bitonic sort od ascending (u64 keys)
#pragma unroll
        for (int k = 2; k <= 16; k <<= 1) {
#pragma unroll
            for (int j = k >> 1; j > 0; j >>= 1) {
#pragma unroll
                for (int i = 0; i < 16; ++i) {
                    const int l = i ^ j;
                    if (l > i) {
                        const bool up = ((i & k) == 0);
                        const unsigned long long a = od[i], c = od[l];
                        const bool sw = up ? (c < a) : (a < c);
                        od[i] = sw ? c : a;
                        od[l] = sw ? a : c;
                    }
                }
            }
        }
        // merge step: bk asc + od asc; low half of bitonic-32 = min(bk[i], od[15-i])
#pragma unroll
        for (int i = 0; i < 16; ++i) {
            const unsigned long long c = od[15 - i];
            bk[i] = (c < bk[i]) ? c : bk[i];
        }
        // bk is bitonic -> sort ascending with stages 8,4,2,1
#pragma unroll
        for (int j = 8; j > 0; j >>= 1) {
#pragma unroll
            for (int i = 0; i < 16; ++i) {
                const int l = i ^ j;
                if (l > i) {
                    const unsigned long long a = bk[i], c = bk[l];
                    const bool sw = (c < a);
                    bk[i] = sw ? c : a;
                    bk[l] = sw ? a : c;
                }
            }
        }
        thr_bits = (unsigned int)(bk[15] >> 32);
    };

    // scan: 512 candidates per lane, threshold check each, compact check per 4
    for (int g = 0; g < 128; ++g) {
#pragma unroll
        for (int u = 0; u < 4; ++u) {
            const int j = (((g << 2) | u) << 3) | l8;
            const float cx = pb[j * 3 + 0];
            const float cy = pb[j * 3 + 1];
            const float cz = pb[j * 3 + 2];
            const float dx = qx - cx, dy = qy - cy, dz = qz - cz;
            // match numpy fp32 exactly: squares + sequential adds, no contraction
            const float d2 = __fadd_rn(__fadd_rn(__fmul_rn(dx, dx), __fmul_rn(dy, dy)),
                                       __fmul_rn(dz, dz));
            if (__float_as_uint(d2) < thr_bits) {
                buf[owptr * NPAD + t] =
                    ((unsigned long long)__float_as_uint(d2) << 32) | (unsigned int)j;
                owptr++;
            }
        }
        if (__any(owptr > OCAP - 4)) compact();
    }
    compact();   // final: bk = exact sorted top-16 for this lane's slice

    // publish sorted per-lane lists into the (now free) buffer columns
#pragma unroll
    for (int s = 0; s < 16; ++s) buf[s * NPAD + t] = bk[s];
    __syncthreads();

    // 8-way merge per query by lane l8==0
    if (l8 == 0) {
        unsigned long long heads[8];
        int hp[8];
        const int base = qloc * 8;
#pragma unroll
        for (int L = 0; L < 8; ++L) { hp[L] = 0; heads[L] = buf[base + L]; }
        const int ob = ((b << 12) | qi) * NK;
        for (int o = 0; o < NK; ++o) {
            unsigned long long bestk = heads[0];
            int bestL = 0;
#pragma unroll
            for (int L = 1; L < 8; ++L) {
                const bool bt = heads[L] < bestk;
                bestk = bt ? heads[L] : bestk;
                bestL = bt ? L : bestL;
            }
            idx_out[ob + o] = (int)(bestk & 0xFFFFFFFFu);
#pragma unroll
            for (int L = 0; L < 8; ++L) {
                if (L == bestL) {
                    hp[L]++;
                    heads[L] = (hp[L] < 16) ? buf[hp[L] * NPAD + base + L] : ~0ull;
                }
            }
        }
    }
}

// ---------------------------------------------------------------------------
// Kernel 2: relation MLP (10->32->64->64) + weighted max-pool over K.
// One thread per (query, k). 16 lanes of a query = one shfl group.
// ---------------------------------------------------------------------------
__global__ __launch_bounds__(256) void mlp_kernel(
    const float* __restrict__ pos, const float* __restrict__ x,
    const int* __restrict__ idx,
    const float* __restrict__ rw1, const float* __restrict__ rb1,
    const float* __restrict__ rw2, const float* __restrict__ rb2,
    const float* __restrict__ rw3, const float* __restrict__ rb3,
    float* __restrict__ pooled) {
    __shared__ float w1s[320], w2s[2048], w3t[4096], b1s[32], b2s[64], b3s[64];
    const int t = threadIdx.x;
    for (int i = t; i < 320; i += 256)  w1s[i] = rw1[i];
    for (int i = t; i < 2048; i += 256) w2s[i] = rw2[i];
    for (int i = t; i < 4096; i += 256) {                 // transpose rw3 -> w3t[o][i]
        const int ii = i >> 6, oo = i & 63;
        w3t[oo * 64 + ii] = rw3[i];
    }
    if (t < 32)                 b1s[t] = rb1[t];
    else if (t >= 32 && t < 96) b2s[t - 32] = rb2[t - 32];
    else if (t >= 96 && t < 160) b3s[t - 96] = rb3[t - 96];
    __syncthreads();

    const int g = blockIdx.x * 256 + t;
    const int k = g & 15;
    const int q = g >> 4;                    // 0..16383
    const int b = q >> 12, n = q & 4095;
    const int j = idx[(size_t)q * NK + k];
    const float* __restrict__ pb = pos + b * (NPTS * 3);

    const float cx = pb[n * 3 + 0], cy = pb[n * 3 + 1], cz = pb[n * 3 + 2];
    const float gx = pb[j * 3 + 0], gy = pb[j * 3 + 1], gz = pb[j * 3 + 2];
    const float rx = gx - cx, ry = gy - cy, rz = gz - cz;
    const float ss = rx * rx + ry * ry + rz * rz;
    const float dis = (ss > 0.f) ? sqrtf(ss) : 0.f;
    const float rin[10] = {cx, cy, cz, gx, gy, gz, rx, ry, rz, dis};

    float h1[32];
#pragma unroll
    for (int o = 0; o < 32; ++o) h1[o] = b1s[o];
#pragma unroll
    for (int i = 0; i < 10; ++i) {
        const float v = rin[i];
#pragma unroll
        for (int o = 0; o < 32; ++o) h1[o] += v * w1s[i * 32 + o];
    }
#pragma unroll
    for (int o = 0; o < 32; ++o) h1[o] = fmaxf(h1[o], 0.f);

    float h2[64];
#pragma unroll
    for (int o = 0; o < 64; ++o) h2[o] = b2s[o];
#pragma unroll
    for (int i = 0; i < 32; ++i) {
        const float v = h1[i];
#pragma unroll
        for (int o = 0; o < 64; ++o) h2[o] += v * w2s[i * 64 + o];
    }
#pragma unroll
    for (int o = 0; o < 64; ++o) h2[o] = fmaxf(h2[o], 0.f);

    const float* __restrict__ xr = x + (size_t)((b << 12) | j) * NC;
    float* __restrict__ pout = pooled + (size_t)q * 64;

    for (int o = 0; o < 64; ++o) {
        float acc = b3s[o];
#pragma unroll
        for (int i = 0; i < 64; i += 4) {
            const float4 wv = *(const float4*)&w3t[o * 64 + i];
            acc += h2[i] * wv.x + h2[i + 1] * wv.y + h2[i + 2] * wv.z + h2[i + 3] * wv.w;
        }
        float f = (o < NC) ? xr[o] : (o == 61 ? gx : (o == 62 ? gy : gz));
        f *= acc;
#pragma unroll
        for (int m = 1; m < 16; m <<= 1) f = fmaxf(f, __shfl_xor(f, m, 16));
        if (k == 0) pout[o] = fmaxf(f, 0.f);   // relu AFTER max-pool
    }
}

// ---------------------------------------------------------------------------
// Kernel 3: y1 = pooled(16384x64) @ fw1(64x128) + fb1 ; accumulate sum/sumsq.
// ---------------------------------------------------------------------------
__global__ __launch_bounds__(256) void gemm1_kernel(
    const float* __restrict__ A, const float* __restrict__ W,
    const float* __restrict__ bias, float* __restrict__ y,
    float* __restrict__ sum, float* __restrict__ sumsq) {
    __shared__ float As[64 * 64];
    __shared__ float Bs[64 * 128];
    const int t = threadIdx.x;
    const int r0 = blockIdx.x * 64;
    for (int i = t; i < 64 * 128; i += 256) Bs[i] = W[i];
    for (int i = t; i < 64 * 64; i += 256)  As[i] = A[(size_t)r0 * 64 + i];
    __syncthreads();

    const int c = t & 127, rg = t >> 7;
    float acc[32];
    const float bv = bias[c];
#pragma unroll
    for (int r = 0; r < 32; ++r) acc[r] = bv;

    for (int kk = 0; kk < 64; kk += 4) {
        const float b0 = Bs[(kk + 0) * 128 + c];
        const float b1 = Bs[(kk + 1) * 128 + c];
        const float b2 = Bs[(kk + 2) * 128 + c];
        const float b3 = Bs[(kk + 3) * 128 + c];
#pragma unroll
        for (int r = 0; r < 32; ++r) {
            const float4 a = *(const float4*)&As[(rg * 32 + r) * 64 + kk];
            acc[r] += a.x * b0 + a.y * b1 + a.z * b2 + a.w * b3;
        }
    }

    float s = 0.f, s2 = 0.f;
#pragma unroll
    for (int r = 0; r < 32; ++r) {
        const float v = acc[r];
        s += v; s2 += v * v;
        y[(size_t)(r0 + rg * 32 + r) * 128 + c] = v;
    }
    __syncthreads();
    As[t] = s; As[256 + t] = s2;
    __syncthreads();
    if (rg == 0) {
        atomicAdd(&sum[c],   As[c] + As[128 + c]);
        atomicAdd(&sumsq[c], As[256 + c] + As[256 + 128 + c]);
    }
}

// ---------------------------------------------------------------------------
// Kernel 4: h1 = relu(bn1(y1)); y2 = h1 @ fw2(128x128) + fb2 ; sum/sumsq.
// BN1 scale/shift computed from sum1/sumsq1 in-kernel. K split 2x64 (<=64KB LDS).
// ---------------------------------------------------------------------------
__global__ __launch_bounds__(256) void gemm2_kernel(
    const float* __restrict__ y1, const float* __restrict__ W,
    const float* __restrict__ bias,
    const float* __restrict__ sum1, const float* __restrict__ sumsq1,
    const float* __restrict__ g1, const float* __restrict__ b1,
    float* __restrict__ y2, float* __restrict__ sum2, float* __restrict__ sumsq2) {
    __shared__ float As[64 * 128];
    __shared__ float Bs[64 * 128];
    __shared__ float a1s[128], s1s[128];
    const int t = threadIdx.x;
    const int r0 = blockIdx.x * 64;

    if (t < 128) {
        const float m = sum1[t] * INV_ROWS;
        const float v = sumsq1[t] * INV_ROWS - m * m;
        const float a = rsqrtf(v + BN_EPS) * g1[t];
        a1s[t] = a; s1s[t] = b1[t] - m * a;
    }
    for (int i = t; i < 64 * 128; i += 256) Bs[i] = W[i];   // fw2 rows 0..63
    __syncthreads();
    for (int i = t; i < 64 * 128; i += 256) {
        const int cc = i & 127;
        const float v = y1[(size_t)r0 * 128 + i];
        As[i] = fmaxf(v * a1s[cc] + s1s[cc], 0.f);
    }
    __syncthreads();

    const int c = t & 127, rg = t >> 7;
    float acc[32];
    const float bv = bias[c];
#pragma unroll
    for (int r = 0; r < 32; ++r) acc[r] = bv;

    for (int kk = 0; kk < 64; kk += 4) {
        const float b0 = Bs[(kk + 0) * 128 + c];
        const float b1v = Bs[(kk + 1) * 128 + c];
        const float b2 = Bs[(kk + 2) * 128 + c];
        const float b3 = Bs[(kk + 3) * 128 + c];
#pragma unroll
        for (int r = 0; r < 32; ++r) {
            const float4 a = *(const float4*)&As[(rg * 32 + r) * 128 + kk];
            acc[r] += a.x * b0 + a.y * b1v + a.z * b2 + a.w * b3;
        }
    }
    __syncthreads();
    for (int i = t; i < 64 * 128; i += 256) Bs[i] = W[64 * 128 + i];  // rows 64..127
    __syncthreads();
    for (int kk = 0; kk < 64; kk += 4) {
        const float b0 = Bs[(kk + 0) * 128 + c];
        const float b1v = Bs[(kk + 1) * 128 + c];
        const float b2 = Bs[(kk + 2) * 128 + c];
        const float b3 = Bs[(kk + 3) * 128 + c];
#pragma unroll
        for (int r = 0; r < 32; ++r) {
            const float4 a = *(const float4*)&As[(rg * 32 + r) * 128 + 64 + kk];
            acc[r] += a.x * b0 + a.y * b1v + a.z * b2 + a.w * b3;
        }
    }

    float s = 0.f, s2 = 0.f;
#pragma unroll
    for (int r = 0; r < 32; ++r) {
        const float v = acc[r];
        s += v; s2 += v * v;
        y2[(size_t)(r0 + rg * 32 + r) * 128 + c] = v;
    }
    __syncthreads();
    As[t] = s; As[256 + t] = s2;
    __syncthreads();
    if (rg == 0) {
        atomicAdd(&sum2[c],   As[c] + As[128 + c]);
        atomicAdd(&sumsq2[c], As[256 + c] + As[256 + 128 + c]);
    }
}

// ---------------------------------------------------------------------------
// Kernel 5: out = bn2(y2)  (no relu on the final stage)
// ---------------------------------------------------------------------------
__global__ __launch_bounds__(256) void bnout_kernel(
    const float* __restrict__ y2, const float* __restrict__ sum2,
    const float* __restrict__ sumsq2, const float* __restrict__ g2,
    const float* __restrict__ b2, float* __restrict__ out) {
    const int i = blockIdx.x * 256 + threadIdx.x;
    const int c = i & 127;
    const float m = sum2[c] * INV_ROWS;
    const float v = sumsq2[c] * INV_ROWS - m * m;
    const float a = rsqrtf(v + BN_EPS) * g2[c];
    out[i] = y2[i] * a + (b2[c] - m * a);
}

extern "C" void kernel_launch(void* const* d_in, const int* in_sizes, int n_in,
                              void* d_out, int out_size, void* d_ws, size_t ws_size,
                              hipStream_t stream) {
    const float* x   = (const float*)d_in[0];
    const float* pos = (const float*)d_in[1];
    const float* rw1 = (const float*)d_in[2];
    const float* rb1 = (const float*)d_in[3];
    const float* rw2 = (const float*)d_in[4];
    const float* rb2 = (const float*)d_in[5];
    const float* rw3 = (const float*)d_in[6];
    const float* rb3 = (const float*)d_in[7];
    const float* fw1 = (const float*)d_in[8];
    const float* fb1 = (const float*)d_in[9];
    const float* g1  = (const float*)d_in[10];
    const float* b1  = (const float*)d_in[11];
    const float* fw2 = (const float*)d_in[12];
    const float* fb2 = (const float*)d_in[13];
    const float* g2  = (const float*)d_in[14];
    const float* b2  = (const float*)d_in[15];
    float* out = (float*)d_out;

    char* ws = (char*)d_ws;
    int*   idx    = (int*)ws;                          // 16384*16 ints   (1 MB)
    float* pooled = (float*)(ws + (1u << 20));         // 16384*64 f32    (4 MB)
    float* y1     = (float*)(ws + (5u << 20));         // 16384*128 f32   (8 MB)
    float* y2     = (float*)(ws + (13u << 20));        // 16384*128 f32   (8 MB)
    float* stats  = (float*)(ws + (21u << 20));        // 4*128 f32
    float* sum1 = stats, *sumsq1 = stats + 128, *sum2 = stats + 256, *sumsq2 = stats + 384;

    hipMemsetAsync(stats, 0, 512 * sizeof(float), stream);

    knn_kernel<<<512, 256, 0, stream>>>(pos, idx);
    mlp_kernel<<<1024, 256, 0, stream>>>(pos, x, idx, rw1, rb1, rw2, rb2, rw3, rb3, pooled);
    gemm1_kernel<<<256, 256, 0, stream>>>(pooled, fw1, fb1, y1, sum1, sumsq1);
    gemm2_kernel<<<256, 256, 0, stream>>>(y1, fw2, fb2, sum1, sumsq1, g1, b1, y2, sum2, sumsq2);
    bnout_kernel<<<NROWS * 128 / 256, 256, 0, stream>>>(y2, sum2, sumsq2, g2, b2, out);
}

// Round 4
// 367.255 us; speedup vs baseline: 1.8634x; 1.1353x over previous
//
#include <hip/hip_runtime.h>
#include <hip/hip_bf16.h>
#include <math.h>

#define NPTS   4096
#define NB     4
#define NC     61
#define NIN    64
#define NOUT   128
#define NK     16
#define NROWS  16384           // NB*NPTS
#define BN_EPS 1e-5f
#define INV_ROWS (1.0f/16384.0f)

// ---------------------------------------------------------------------------
// Kernel 0: pack pos (Nx3) into float4 (Nx4) for single-load candidates.
// ---------------------------------------------------------------------------
__global__ __launch_bounds__(256) void prep_pos4(const float* __restrict__ pos,
                                                 float4* __restrict__ pos4) {
    const int i = blockIdx.x * 256 + threadIdx.x;
    if (i < NB * NPTS)
        pos4[i] = make_float4(pos[i * 3 + 0], pos[i * 3 + 1], pos[i * 3 + 2], 0.f);
}

// ---------------------------------------------------------------------------
// Kernel 1: exact KNN (top-16 smallest d2, tie-break by smaller index).
// 1024 blocks x 256 threads; 16 queries/block, 16 lanes/query (lane L scans
// j % 16 == L, 256 candidates each). Selection via packed u64 keys
// (d2_bits<<32 | idx): register-resident sorted top-16 per lane; cheap
// threshold scan appends survivors to a per-lane LDS column; wave-uniform
// bitonic compaction only when any lane's column nears full (~6x/scan).
// Final: 16-way lexicographic merge of sorted per-lane lists.
// ---------------------------------------------------------------------------
#define OCAP 16
#define NPAD 257               // column stride (u64 entries)

__global__ __launch_bounds__(256) void knn_kernel(const float4* __restrict__ pos4,
                                                  int* __restrict__ idx_out) {
    __shared__ unsigned long long buf[OCAP * NPAD];
    const int t  = threadIdx.x;
    const int b  = blockIdx.x >> 8;            // 256 blocks per batch
    const int q0 = (blockIdx.x & 255) * 16;
    const float4* __restrict__ pb = pos4 + b * NPTS;

    const int qloc = t >> 4;
    const int l16  = t & 15;
    const int qi   = q0 + qloc;

    const float4 qp = pb[qi];
    const float qx = qp.x, qy = qp.y, qz = qp.z;

    unsigned long long bk[16];
#pragma unroll
    for (int i = 0; i < 16; ++i) bk[i] = ~0ull;
    unsigned int thr_bits = 0xFFFFFFFFu;
    int owptr = 0;

    auto compact = [&]() {
        unsigned long long od[16];
#pragma unroll
        for (int s = 0; s < OCAP; ++s) {
            const unsigned long long v = buf[s * NPAD + t];
            od[s] = (s < owptr) ? v : ~0ull;
        }
        owptr = 0;
        // bitonic sort od ascending (u64 keys)
#pragma unroll
        for (int k = 2; k <= 16; k <<= 1) {
#pragma unroll
            for (int j = k >> 1; j > 0; j >>= 1) {
#pragma unroll
                for (int i = 0; i < 16; ++i) {
                    const int l = i ^ j;
                    if (l > i) {
                        const bool up = ((i & k) == 0);
                        const unsigned long long a = od[i], c = od[l];
                        const bool sw = up ? (c < a) : (a < c);
                        od[i] = sw ? c : a;
                        od[l] = sw ? a : c;
                    }
                }
            }
        }
        // merge: bk asc + od asc; low half of bitonic-32 = min(bk[i], od[15-i])
#pragma unroll
        for (int i = 0; i < 16; ++i) {
            const unsigned long long c = od[15 - i];
            bk[i] = (c < bk[i]) ? c : bk[i];
        }
        // bk is bitonic -> sort ascending with stages 8,4,2,1
#pragma unroll
        for (int j = 8; j > 0; j >>= 1) {
#pragma unroll
            for (int i = 0; i < 16; ++i) {
                const int l = i ^ j;
                if (l > i) {
                    const unsigned long long a = bk[i], c = bk[l];
                    const bool sw = (c < a);
                    bk[i] = sw ? c : a;
                    bk[l] = sw ? a : c;
                }
            }
        }
        thr_bits = (unsigned int)(bk[15] >> 32);
    };

    // scan: 256 candidates per lane, threshold check each, compact check per 4
    for (int g = 0; g < 64; ++g) {
#pragma unroll
        for (int u = 0; u < 4; ++u) {
            const int j = (((g << 2) | u) << 4) | l16;
            const float4 p = pb[j];
            const float dx = qx - p.x, dy = qy - p.y, dz = qz - p.z;
            // match numpy fp32 exactly: squares + sequential adds, no contraction
            const float d2 = __fadd_rn(__fadd_rn(__fmul_rn(dx, dx), __fmul_rn(dy, dy)),
                                       __fmul_rn(dz, dz));
            if (__float_as_uint(d2) < thr_bits) {
                buf[owptr * NPAD + t] =
                    ((unsigned long long)__float_as_uint(d2) << 32) | (unsigned int)j;
                owptr++;
            }
        }
        if (__any(owptr > OCAP - 4)) compact();
    }
    compact();   // final: bk = exact sorted top-16 for this lane's slice

    // publish sorted per-lane lists into the (now free) buffer columns
#pragma unroll
    for (int s = 0; s < 16; ++s) buf[s * NPAD + t] = bk[s];
    __syncthreads();

    // 16-way merge per query by lane l16==0
    if (l16 == 0) {
        unsigned long long heads[16];
        int hp[16];
        const int base = qloc * 16;
#pragma unroll
        for (int L = 0; L < 16; ++L) { hp[L] = 0; heads[L] = buf[base + L]; }
        const int ob = ((b << 12) | qi) * NK;
        for (int o = 0; o < NK; ++o) {
            unsigned long long bestk = heads[0];
            int bestL = 0;
#pragma unroll
            for (int L = 1; L < 16; ++L) {
                const bool bt = heads[L] < bestk;
                bestk = bt ? heads[L] : bestk;
                bestL = bt ? L : bestL;
            }
            idx_out[ob + o] = (int)(bestk & 0xFFFFFFFFu);
#pragma unroll
            for (int L = 0; L < 16; ++L) {
                if (L == bestL) {
                    hp[L]++;
                    heads[L] = (hp[L] < 16) ? buf[hp[L] * NPAD + base + L] : ~0ull;
                }
            }
        }
    }
}

// ---------------------------------------------------------------------------
// Kernel 2: relation MLP (10->32->64->64) + weighted max-pool over K.
// 2 items per thread (k and k+8 of the same query): every wave-uniform
// weight ds_read feeds 2x the FMAs -> LDS-pipe pressure halves.
// 8 lanes per query; pool = per-thread max of 2 items + shfl_xor width 8.
// ---------------------------------------------------------------------------
__global__ __launch_bounds__(256) void mlp_kernel(
    const float4* __restrict__ pos4, const float* __restrict__ x,
    const int* __restrict__ idx,
    const float* __restrict__ rw1, const float* __restrict__ rb1,
    const float* __restrict__ rw2, const float* __restrict__ rb2,
    const float* __restrict__ rw3, const float* __restrict__ rb3,
    float* __restrict__ pooled) {
    __shared__ float w1s[320], w2s[2048], w3t[4096], b1s[32], b2s[64], b3s[64];
    const int t = threadIdx.x;
    for (int i = t; i < 320; i += 256)  w1s[i] = rw1[i];
    for (int i = t; i < 2048; i += 256) w2s[i] = rw2[i];
    for (int i = t; i < 4096; i += 256) {                 // transpose rw3 -> w3t[o][i]
        const int ii = i >> 6, oo = i & 63;
        w3t[oo * 64 + ii] = rw3[i];
    }
    if (t < 32)                 b1s[t] = rb1[t];
    else if (t >= 32 && t < 96) b2s[t - 32] = rb2[t - 32];
    else if (t >= 96 && t < 160) b3s[t - 96] = rb3[t - 96];
    __syncthreads();

    const int k8   = t & 7;
    const int qloc = t >> 3;                   // 32 queries per block
    const int q    = blockIdx.x * 32 + qloc;   // 0..16383
    const int b    = q >> 12, n = q & 4095;
    const int j0 = idx[(size_t)q * NK + k8];
    const int j1 = idx[(size_t)q * NK + k8 + 8];
    const float4* __restrict__ pb = pos4 + b * NPTS;

    const float4 cp = pb[n];
    const float4 pa = pb[j0];
    const float4 pc = pb[j1];
    const float rxa = pa.x - cp.x, rya = pa.y - cp.y, rza = pa.z - cp.z;
    const float rxb = pc.x - cp.x, ryb = pc.y - cp.y, rzb = pc.z - cp.z;
    const float ssa = rxa * rxa + rya * rya + rza * rza;
    const float ssb = rxb * rxb + ryb * ryb + rzb * rzb;
    const float disa = (ssa > 0.f) ? sqrtf(ssa) : 0.f;
    const float disb = (ssb > 0.f) ? sqrtf(ssb) : 0.f;
    const float rina[10] = {cp.x, cp.y, cp.z, pa.x, pa.y, pa.z, rxa, rya, rza, disa};
    const float rinb[10] = {cp.x, cp.y, cp.z, pc.x, pc.y, pc.z, rxb, ryb, rzb, disb};

    float h1a[32], h1b[32];
#pragma unroll
    for (int o = 0; o < 32; ++o) { h1a[o] = b1s[o]; h1b[o] = h1a[o]; }
#pragma unroll
    for (int i = 0; i < 10; ++i) {
        const float va = rina[i], vb = rinb[i];
#pragma unroll
        for (int o = 0; o < 32; ++o) {
            const float w = w1s[i * 32 + o];
            h1a[o] += va * w; h1b[o] += vb * w;
        }
    }
#pragma unroll
    for (int o = 0; o < 32; ++o) { h1a[o] = fmaxf(h1a[o], 0.f); h1b[o] = fmaxf(h1b[o], 0.f); }

    float h2a[64], h2b[64];
#pragma unroll
    for (int o = 0; o < 64; ++o) { h2a[o] = b2s[o]; h2b[o] = h2a[o]; }
#pragma unroll
    for (int i = 0; i < 32; ++i) {
        const float va = h1a[i], vb = h1b[i];
#pragma unroll
        for (int o = 0; o < 64; ++o) {
            const float w = w2s[i * 64 + o];
            h2a[o] += va * w; h2b[o] += vb * w;
        }
    }
#pragma unroll
    for (int o = 0; o < 64; ++o) { h2a[o] = fmaxf(h2a[o], 0.f); h2b[o] = fmaxf(h2b[o], 0.f); }

    const float* __restrict__ xr0 = x + (size_t)((b << 12) | j0) * NC;
    const float* __restrict__ xr1 = x + (size_t)((b << 12) | j1) * NC;
    float* __restrict__ pout = pooled + (size_t)q * 64;

    for (int o = 0; o < 64; ++o) {
        float acca = b3s[o], accb = acca;
#pragma unroll
        for (int i = 0; i < 64; i += 4) {
            const float4 wv = *(const float4*)&w3t[o * 64 + i];
            acca += h2a[i] * wv.x + h2a[i + 1] * wv.y + h2a[i + 2] * wv.z + h2a[i + 3] * wv.w;
            accb += h2b[i] * wv.x + h2b[i + 1] * wv.y + h2b[i + 2] * wv.z + h2b[i + 3] * wv.w;
        }
        const float fa = (o < NC) ? xr0[o] : (o == 61 ? pa.x : (o == 62 ? pa.y : pa.z));
        const float fb = (o < NC) ? xr1[o] : (o == 61 ? pc.x : (o == 62 ? pc.y : pc.z));
        float f = fmaxf(fa * acca, fb * accb);
#pragma unroll
        for (int m = 1; m < 8; m <<= 1) f = fmaxf(f, __shfl_xor(f, m, 8));
        if (k8 == 0) pout[o] = fmaxf(f, 0.f);   // relu AFTER max-pool
    }
}

// ---------------------------------------------------------------------------
// Kernel 3: y1 = pooled(16384x64) @ fw1(64x128) + fb1 ; accumulate sum/sumsq.
// ---------------------------------------------------------------------------
__global__ __launch_bounds__(256) void gemm1_kernel(
    const float* __restrict__ A, const float* __restrict__ W,
    const float* __restrict__ bias, float* __restrict__ y,
    float* __restrict__ sum, float* __restrict__ sumsq) {
    __shared__ float As[64 * 64];
    __shared__ float Bs[64 * 128];
    const int t = threadIdx.x;
    const int r0 = blockIdx.x * 64;
    for (int i = t; i < 64 * 128; i += 256) Bs[i] = W[i];
    for (int i = t; i < 64 * 64; i += 256)  As[i] = A[(size_t)r0 * 64 + i];
    __syncthreads();

    const int c = t & 127, rg = t >> 7;
    float acc[32];
    const float bv = bias[c];
#pragma unroll
    for (int r = 0; r < 32; ++r) acc[r] = bv;

    for (int kk = 0; kk < 64; kk += 4) {
        const float b0 = Bs[(kk + 0) * 128 + c];
        const float b1 = Bs[(kk + 1) * 128 + c];
        const float b2 = Bs[(kk + 2) * 128 + c];
        const float b3 = Bs[(kk + 3) * 128 + c];
#pragma unroll
        for (int r = 0; r < 32; ++r) {
            const float4 a = *(const float4*)&As[(rg * 32 + r) * 64 + kk];
            acc[r] += a.x * b0 + a.y * b1 + a.z * b2 + a.w * b3;
        }
    }

    float s = 0.f, s2 = 0.f;
#pragma unroll
    for (int r = 0; r < 32; ++r) {
        const float v = acc[r];
        s += v; s2 += v * v;
        y[(size_t)(r0 + rg * 32 + r) * 128 + c] = v;
    }
    __syncthreads();
    As[t] = s; As[256 + t] = s2;
    __syncthreads();
    if (rg == 0) {
        atomicAdd(&sum[c],   As[c] + As[128 + c]);
        atomicAdd(&sumsq[c], As[256 + c] + As[256 + 128 + c]);
    }
}

// ---------------------------------------------------------------------------
// Kernel 4: h1 = relu(bn1(y1)); y2 = h1 @ fw2(128x128) + fb2 ; sum/sumsq.
// BN1 scale/shift computed from sum1/sumsq1 in-kernel. K split 2x64 (<=64KB LDS).
// ---------------------------------------------------------------------------
__global__ __launch_bounds__(256) void gemm2_kernel(
    const float* __restrict__ y1, const float* __restrict__ W,
    const float* __restrict__ bias,
    const float* __restrict__ sum1, const float* __restrict__ sumsq1,
    const float* __restrict__ g1, const float* __restrict__ b1,
    float* __restrict__ y2, float* __restrict__ sum2, float* __restrict__ sumsq2) {
    __shared__ float As[64 * 128];
    __shared__ float Bs[64 * 128];
    __shared__ float a1s[128], s1s[128];
    const int t = threadIdx.x;
    const int r0 = blockIdx.x * 64;

    if (t < 128) {
        const float m = sum1[t] * INV_ROWS;
        const float v = sumsq1[t] * INV_ROWS - m * m;
        const float a = rsqrtf(v + BN_EPS) * g1[t];
        a1s[t] = a; s1s[t] = b1[t] - m * a;
    }
    for (int i = t; i < 64 * 128; i += 256) Bs[i] = W[i];   // fw2 rows 0..63
    __syncthreads();
    for (int i = t; i < 64 * 128; i += 256) {
        const int cc = i & 127;
        const float v = y1[(size_t)r0 * 128 + i];
        As[i] = fmaxf(v * a1s[cc] + s1s[cc], 0.f);
    }
    __syncthreads();

    const int c = t & 127, rg = t >> 7;
    float acc[32];
    const float bv = bias[c];
#pragma unroll
    for (int r = 0; r < 32; ++r) acc[r] = bv;

    for (int kk = 0; kk < 64; kk += 4) {
        const float b0 = Bs[(kk + 0) * 128 + c];
        const float b1v = Bs[(kk + 1) * 128 + c];
        const float b2 = Bs[(kk + 2) * 128 + c];
        const float b3 = Bs[(kk + 3) * 128 + c];
#pragma unroll
        for (int r = 0; r < 32; ++r) {
            const float4 a = *(const float4*)&As[(rg * 32 + r) * 128 + kk];
            acc[r] += a.x * b0 + a.y * b1v + a.z * b2 + a.w * b3;
        }
    }
    __syncthreads();
    for (int i = t; i < 64 * 128; i += 256) Bs[i] = W[64 * 128 + i];  // rows 64..127
    __syncthreads();
    for (int kk = 0; kk < 64; kk += 4) {
        const float b0 = Bs[(kk + 0) * 128 + c];
        const float b1v = Bs[(kk + 1) * 128 + c];
        const float b2 = Bs[(kk + 2) * 128 + c];
        const float b3 = Bs[(kk + 3) * 128 + c];
#pragma unroll
        for (int r = 0; r < 32; ++r) {
            const float4 a = *(const float4*)&As[(rg * 32 + r) * 128 + 64 + kk];
            acc[r] += a.x * b0 + a.y * b1v + a.z * b2 + a.w * b3;
        }
    }

    float s = 0.f, s2 = 0.f;
#pragma unroll
    for (int r = 0; r < 32; ++r) {
        const float v = acc[r];
        s += v; s2 += v * v;
        y2[(size_t)(r0 + rg * 32 + r) * 128 + c] = v;
    }
    __syncthreads();
    As[t] = s; As[256 + t] = s2;
    __syncthreads();
    if (rg == 0) {
        atomicAdd(&sum2[c],   As[c] + As[128 + c]);
        atomicAdd(&sumsq2[c], As[256 + c] + As[256 + 128 + c]);
    }
}

// ---------------------------------------------------------------------------
// Kernel 5: out = bn2(y2)  (no relu on the final stage)
// ---------------------------------------------------------------------------
__global__ __launch_bounds__(256) void bnout_kernel(
    const float* __restrict__ y2, const float* __restrict__ sum2,
    const float* __restrict__ sumsq2, const float* __restrict__ g2,
    const float* __restrict__ b2, float* __restrict__ out) {
    const int i = blockIdx.x * 256 + threadIdx.x;
    const int c = i & 127;
    const float m = sum2[c] * INV_ROWS;
    const float v = sumsq2[c] * INV_ROWS - m * m;
    const float a = rsqrtf(v + BN_EPS) * g2[c];
    out[i] = y2[i] * a + (b2[c] - m * a);
}

extern "C" void kernel_launch(void* const* d_in, const int* in_sizes, int n_in,
                              void* d_out, int out_size, void* d_ws, size_t ws_size,
                              hipStream_t stream) {
    const float* x   = (const float*)d_in[0];
    const float* pos = (const float*)d_in[1];
    const float* rw1 = (const float*)d_in[2];
    const float* rb1 = (const float*)d_in[3];
    const float* rw2 = (const float*)d_in[4];
    const float* rb2 = (const float*)d_in[5];
    const float* rw3 = (const float*)d_in[6];
    const float* rb3 = (const float*)d_in[7];
    const float* fw1 = (const float*)d_in[8];
    const float* fb1 = (const float*)d_in[9];
    const float* g1  = (const float*)d_in[10];
    const float* b1  = (const float*)d_in[11];
    const float* fw2 = (const float*)d_in[12];
    const float* fb2 = (const float*)d_in[13];
    const float* g2  = (const float*)d_in[14];
    const float* b2  = (const float*)d_in[15];
    float* out = (float*)d_out;

    char* ws = (char*)d_ws;
    int*    idx    = (int*)ws;                         // 16384*16 ints   (1 MB)
    float*  pooled = (float*)(ws + (1u << 20));        // 16384*64 f32    (4 MB)
    float*  y1     = (float*)(ws + (5u << 20));        // 16384*128 f32   (8 MB)
    float*  y2     = (float*)(ws + (13u << 20));       // 16384*128 f32   (8 MB)
    float*  stats  = (float*)(ws + (21u << 20));       // 4*128 f32
    float4* pos4   = (float4*)(ws + (22u << 20));      // 16384 float4    (256 KB)
    float* sum1 = stats, *sumsq1 = stats + 128, *sum2 = stats + 256, *sumsq2 = stats + 384;

    hipMemsetAsync(stats, 0, 512 * sizeof(float), stream);

    prep_pos4<<<64, 256, 0, stream>>>(pos, pos4);
    knn_kernel<<<1024, 256, 0, stream>>>(pos4, idx);
    mlp_kernel<<<512, 256, 0, stream>>>(pos4, x, idx, rw1, rb1, rw2, rb2, rw3, rb3, pooled);
    gemm1_kernel<<<256, 256, 0, stream>>>(pooled, fw1, fb1, y1, sum1, sumsq1);
    gemm2_kernel<<<256, 256, 0, stream>>>(y1, fw2, fb2, sum1, sumsq1, g1, b1, y2, sum2, sumsq2);
    bnout_kernel<<<NROWS * 128 / 256, 256, 0, stream>>>(y2, sum2, sumsq2, g2, b2, out);
}